// Round 14
// baseline (1142.495 us; speedup 1.0000x reference)
//
#include <hip/hip_runtime.h>
#include <math.h>

// Sliced Wasserstein-2: for each (b,c,p): W2^2 = mean_i (sort(X@theta_p) - sort(Y@theta_p))^2
// loss = mean_{b,c} sqrt(mean_p W2^2)
//
// R14: two more layout-merges on top of R13 (two-kernel split, VGPR<=48,
// zero spill):
//  - merge a=12 via L4 (reg = i[11:7]): 128 DS vs 192 (stage_lds + 4 bperm)
//  - merge a=13 via L5 (reg = i[12:8]) + m=4 bperm: 160 DS vs 192 (high3)
// DS ops/thread/sort 1088 -> 992; stage_lds eliminated; 3 fewer serial
// bpermute stages. All transpose legs <=2-way under pad A(i)=i+(i>>5).

namespace {
constexpr int Bb = 8, Cc = 4, Nn = 32768, Pp = 50;
constexpr int THREADS = 1024;
constexpr int VPT = 32;                    // values per thread
constexpr int SLICES = Bb * Cc * Pp;       // 1600
constexpr size_t W2_BYTES = 8192;          // w2[1600] rounded up
constexpr int LDS_FLOATS = Nn + (Nn >> 5); // padded buffer: 33792 floats
}

__device__ __forceinline__ void ce(float& a, float& b, bool up) {
  float lo = fminf(a, b);
  float hi = fmaxf(a, b);
  a = up ? lo : hi;
  b = up ? hi : lo;
}

// 2-VALU compare-select CE: keepMin ? min(v,o) : max(v,o); ties resolve
// consistently on both partners (multiset preserved).
__device__ __forceinline__ float sel_ce(float v, float o, bool keepMin) {
  return ((o < v) != keepMin) ? v : o;
}

__device__ __forceinline__ float dpp_xor(float x, int ctrl_sel) {
  // 0xB1 = quad_perm(1,0,3,2) = xor1; 0x4E = quad_perm(2,3,0,1) = xor2
  int i = ctrl_sel == 0xB1
    ? __builtin_amdgcn_update_dpp(0, __float_as_int(x), 0xB1, 0xF, 0xF, true)
    : __builtin_amdgcn_update_dpp(0, __float_as_int(x), 0x4E, 0xF, 0xF, true);
  return __int_as_float(i);
}

// cross-lane CE stage with xor-mask M (M=1,2 via DPP; M>=4 via ds_bpermute)
template<int M>
__device__ __forceinline__ void stage_xlane(float v[VPT], int tid, bool up) {
  const bool keepMin = (up == ((tid & M) == 0));
  if constexpr (M == 1 || M == 2) {
    constexpr int ctrl = (M == 1) ? 0xB1 : 0x4E;
#pragma unroll
    for (int r = 0; r < VPT; r++) {
      float o = dpp_xor(v[r], ctrl);
      v[r] = sel_ce(v[r], o, keepMin);
    }
  } else {
    const int addr = (((tid & 63) ^ M) << 2);
#pragma unroll
    for (int r = 0; r < VPT; r++) {
      float o = __int_as_float(
          __builtin_amdgcn_ds_bpermute(addr, __float_as_int(v[r])));
      v[r] = sel_ce(v[r], o, keepMin);
    }
  }
}

// 5-stage in-register network on the reg-index bits (j=16..1), direction
// uniform per thread via sign-flip trick.
__device__ __forceinline__ void tail_inreg(float v[VPT], bool up) {
  const unsigned flip = up ? 0u : 0x80000000u;
#pragma unroll
  for (int r = 0; r < VPT; r++)
    v[r] = __int_as_float(__float_as_int(v[r]) ^ flip);
#pragma unroll
  for (int j = 16; j > 0; j >>= 1) {
#pragma unroll
    for (int r = 0; r < VPT; r++) {
      if (!(r & j)) {
        float a = v[r], b = v[r | j];
        v[r] = fminf(a, b);
        v[r | j] = fmaxf(a, b);
      }
    }
  }
#pragma unroll
  for (int r = 0; r < VPT; r++)
    v[r] = __int_as_float(__float_as_int(v[r]) ^ flip);
}

// wave-local cross stages (m = MTOP..1) + tail, for merge k = 2^A (A<=11)
template<int A, int MTOP>
__device__ __forceinline__ void wave_stages_and_tail(float v[VPT], int tid) {
  const bool up = ((tid & (1 << (A - 5))) == 0);
  if constexpr (MTOP >= 32) stage_xlane<32>(v, tid, up);
  if constexpr (MTOP >= 16) stage_xlane<16>(v, tid, up);
  if constexpr (MTOP >= 8)  stage_xlane<8>(v, tid, up);
  if constexpr (MTOP >= 4)  stage_xlane<4>(v, tid, up);
  if constexpr (MTOP >= 2)  stage_xlane<2>(v, tid, up);
  if constexpr (MTOP >= 1)  stage_xlane<1>(v, tid, up);
  tail_inreg(v, up);
}

// Mid-layout trip: reg = i[LOW+4 : LOW], lanes hold i[LOW-1:0] and i[14:LOW+5].
// Runs the 5-stage reg network (tail_inreg) on bits LOW+4..LOW with uniform
// direction `up`, via L0 -> Lmid -> L0. Pad keeps all legs <=2-way.
template<int LOW>
__device__ __forceinline__ void merge_mid_trip(float v[VPT], float* s, int tid,
                                               bool up) {
  const int base = tid * VPT;
  const int hi = (tid >> LOW) << (LOW + 5);
  const int lo = tid & ((1 << LOW) - 1);
  __syncthreads();                      // prior users of s must finish
#pragma unroll
  for (int r = 0; r < VPT; r++) { int i = base + r; s[i + (i >> 5)] = v[r]; }
  __syncthreads();
#pragma unroll
  for (int r = 0; r < VPT; r++) { int i = hi | (r << LOW) | lo; v[r] = s[i + (i >> 5)]; }
  tail_inreg(v, up);                    // bits LOW+4..LOW, reg-index order
  // write back own Lmid slots (no barrier: same slots just read)
#pragma unroll
  for (int r = 0; r < VPT; r++) { int i = hi | (r << LOW) | lo; s[i + (i >> 5)] = v[r]; }
  __syncthreads();
#pragma unroll
  for (int r = 0; r < VPT; r++) { int i = base + r; v[r] = s[i + (i >> 5)]; }
}

// Merge k=2^A (A=14,15) entirely in-register via three layouts:
//  L0: i = tid<<5 | r        (reg = i[4:0])
//  L2: i = r2<<10 | tid      (reg = i[14:10]) -> stages b(A-1)..b10
//  L3: i = tid[9:5]<<10 | r3<<5 | tid[4:0] (reg = i[9:5]) -> stages b9..b5
// Caller finishes with tail_inreg in L0 (stages b4..b0).
template<int A>
__device__ __forceinline__ void merge_high3(float v[VPT], float* s, int tid) {
  const int base = tid * VPT;
  // ---- L0 -> L2 ----
  __syncthreads();                      // prior users of s must finish
#pragma unroll
  for (int r = 0; r < VPT; r++) { int i = base + r; s[i + (i >> 5)] = v[r]; }
  __syncthreads();
#pragma unroll
  for (int r2 = 0; r2 < VPT; r2++) { int i = (r2 << 10) | tid; v[r2] = s[i + (i >> 5)]; }
  // ---- stages b(A-1)..b10 on reg bits, compile-time dirs ----
#pragma unroll
  for (int bb = A - 11; bb >= 0; bb--) {
    const int j = 1 << bb;
#pragma unroll
    for (int r2 = 0; r2 < VPT; r2++) {
      if (!(r2 & j)) {
        bool upv = (A == 15) ? true : (((r2 >> (A - 10)) & 1) == 0);
        ce(v[r2], v[r2 | j], upv);
      }
    }
  }
  // ---- L2 -> L3 (rewrite own L2 slots: no barrier before write) ----
#pragma unroll
  for (int r2 = 0; r2 < VPT; r2++) { int i = (r2 << 10) | tid; s[i + (i >> 5)] = v[r2]; }
  __syncthreads();
  const int hi = (tid >> 5) << 10;      // tid[9:5] -> i[14:10]
  const int lo = tid & 31;              // tid[4:0] -> i[4:0]
#pragma unroll
  for (int r3 = 0; r3 < VPT; r3++) { int i = hi | (r3 << 5) | lo; v[r3] = s[i + (i >> 5)]; }
  // ---- stages b9..b5: dir = bit A of i = tid bit (A-5), thread-uniform ----
  const bool up = (A == 15) ? true : ((tid & (1 << (A - 5))) == 0);
  tail_inreg(v, up);
  // ---- L3 -> L0 (rewrite own L3 slots: no barrier before write) ----
#pragma unroll
  for (int r3 = 0; r3 < VPT; r3++) { int i = hi | (r3 << 5) | lo; s[i + (i >> 5)] = v[r3]; }
  __syncthreads();
#pragma unroll
  for (int r = 0; r < VPT; r++) { int i = base + r; v[r] = s[i + (i >> 5)]; }
}

// Full distributed bitonic sort: rank of v[r] on thread tid is tid*32 + r.
__device__ __forceinline__ void sort_dist(float v[VPT], float* s, int tid) {
  // merges a=1..4 (k=2..16): in-register, compile-time directions
#pragma unroll
  for (int k = 2; k <= 16; k <<= 1) {
#pragma unroll
    for (int j = k >> 1; j > 0; j >>= 1) {
#pragma unroll
      for (int r = 0; r < VPT; r++)
        if (!(r & j)) ce(v[r], v[r | j], (r & k) == 0);
    }
  }
  // a=5 (k=32): dir = tid bit0, all stages in-register
  tail_inreg(v, (tid & 1) == 0);
  // a=6..11: wave-local exchanges + tail
  wave_stages_and_tail<6, 1>(v, tid);
  wave_stages_and_tail<7, 2>(v, tid);
  wave_stages_and_tail<8, 4>(v, tid);
  wave_stages_and_tail<9, 8>(v, tid);
  wave_stages_and_tail<10, 16>(v, tid);
  wave_stages_and_tail<11, 32>(v, tid);
  // a=12: L4 trip (bits 11..7 in-reg), then bits 6,5 dpp + tail
  {
    const bool up = (tid & 128) == 0;       // i bit12 = tid bit7
    merge_mid_trip<7>(v, s, tid, up);
    stage_xlane<2>(v, tid, up);
    stage_xlane<1>(v, tid, up);
    tail_inreg(v, up);
  }
  // a=13: L5 trip (bits 12..8 in-reg), then bit7 bperm + bits 6,5 dpp + tail
  {
    const bool up = (tid & 256) == 0;       // i bit13 = tid bit8
    merge_mid_trip<8>(v, s, tid, up);
    stage_xlane<4>(v, tid, up);
    stage_xlane<2>(v, tid, up);
    stage_xlane<1>(v, tid, up);
    tail_inreg(v, up);
  }
  // a=14,15: three-layout merges + L0 tail
  merge_high3<14>(v, s, tid);
  tail_inreg(v, (tid & 512) == 0);
  merge_high3<15>(v, s, tid);
  tail_inreg(v, true);
}

__device__ __forceinline__ void project_slice(const float4* base, float t0, float t1,
                                              int tid, float v[VPT]) {
#pragma unroll
  for (int q = 0; q < VPT / 2; q++) {
    float4 u = base[tid * (VPT / 2) + q];
    v[2 * q]     = fmaf(u.x, t0, u.y * t1);
    v[2 * q + 1] = fmaf(u.z, t0, u.w * t1);
  }
}

// ---- kernel A: sort X slice, stage sorted run in scratch ----
extern "C" __global__ void __launch_bounds__(THREADS)
swd_sortx(const float* __restrict__ x, const float* __restrict__ proj,
          float* __restrict__ xs, int slice_base) {
  extern __shared__ float s[];
  const int slice = slice_base + blockIdx.x;
  const int p  = slice % Pp;
  const int bc = slice / Pp;
  const int tid = threadIdx.x;
  const float t0 = proj[2 * p];
  const float t1 = proj[2 * p + 1];
  float v[VPT];
  project_slice((const float4*)(x + (size_t)bc * Nn * 2), t0, t1, tid, v);
  sort_dist(v, s, tid);
  float4* o = (float4*)(xs + (size_t)blockIdx.x * Nn + tid * VPT);
#pragma unroll
  for (int q = 0; q < VPT / 4; q++)
    o[q] = make_float4(v[4 * q], v[4 * q + 1], v[4 * q + 2], v[4 * q + 3]);
}

// ---- kernel B: sort Y slice, diff against staged sorted X, reduce ----
extern "C" __global__ void __launch_bounds__(THREADS)
swd_sorty(const float* __restrict__ y, const float* __restrict__ proj,
          const float* __restrict__ xs, float* __restrict__ w2, int slice_base) {
  extern __shared__ float s[];
  __shared__ float wsum[THREADS / 64];
  const int slice = slice_base + blockIdx.x;
  const int p  = slice % Pp;
  const int bc = slice / Pp;
  const int tid = threadIdx.x;
  const float t0 = proj[2 * p];
  const float t1 = proj[2 * p + 1];
  float v[VPT];
  project_slice((const float4*)(y + (size_t)bc * Nn * 2), t0, t1, tid, v);
  sort_dist(v, s, tid);

  const float4* xr = (const float4*)(xs + (size_t)blockIdx.x * Nn + tid * VPT);
  float acc = 0.f;
#pragma unroll
  for (int q = 0; q < VPT / 4; q++) {
    float4 u = xr[q];
    float d0 = u.x - v[4 * q];
    float d1 = u.y - v[4 * q + 1];
    float d2 = u.z - v[4 * q + 2];
    float d3 = u.w - v[4 * q + 3];
    acc = fmaf(d0, d0, acc);
    acc = fmaf(d1, d1, acc);
    acc = fmaf(d2, d2, acc);
    acc = fmaf(d3, d3, acc);
  }
#pragma unroll
  for (int off = 32; off > 0; off >>= 1)
    acc += __shfl_down(acc, off, 64);
  if ((tid & 63) == 0) wsum[tid >> 6] = acc;
  __syncthreads();
  if (tid == 0) {
    float t = 0.f;
#pragma unroll
    for (int w = 0; w < THREADS / 64; w++) t += wsum[w];
    w2[slice] = t * (1.0f / Nn);
  }
}

extern "C" __global__ void swd_final(const float* __restrict__ w2,
                                     float* __restrict__ out) {
  __shared__ float sred[Bb * Cc];
  int t = threadIdx.x;
  if (t < Bb * Cc) {
    float sum = 0.f;
    for (int p = 0; p < Pp; p++) sum += w2[t * Pp + p];
    sred[t] = sqrtf(sum * (1.0f / Pp));
  }
  __syncthreads();
  if (t == 0) {
    float a = 0.f;
    for (int i = 0; i < Bb * Cc; i++) a += sred[i];
    out[0] = a * (1.0f / (Bb * Cc));
  }
}

extern "C" void kernel_launch(void* const* d_in, const int* in_sizes, int n_in,
                              void* d_out, int out_size, void* d_ws, size_t ws_size,
                              hipStream_t stream) {
  const float* x    = (const float*)d_in[0];
  const float* y    = (const float*)d_in[1];
  const float* proj = (const float*)d_in[2];
  float* w2  = (float*)d_ws;                       // first 8KB of scratch
  float* xs  = (float*)((char*)d_ws + W2_BYTES);   // sorted-X staging
  float* out = (float*)d_out;

  const size_t lds = (size_t)LDS_FLOATS * sizeof(float);  // 132 KB
  (void)hipFuncSetAttribute((const void*)swd_sortx,
                            hipFuncAttributeMaxDynamicSharedMemorySize, (int)lds);
  (void)hipFuncSetAttribute((const void*)swd_sorty,
                            hipFuncAttributeMaxDynamicSharedMemorySize, (int)lds);

  const size_t slice_bytes = (size_t)Nn * sizeof(float);
  const size_t avail = ws_size > W2_BYTES ? ws_size - W2_BYTES : 0;
  int chunk = (int)(avail / slice_bytes);
  if (chunk > SLICES) chunk = SLICES;
  if (chunk < 1) chunk = 1;

  for (int base = 0; base < SLICES; base += chunk) {
    int n = SLICES - base < chunk ? SLICES - base : chunk;
    hipLaunchKernelGGL(swd_sortx, dim3(n), dim3(THREADS), lds, stream,
                       x, proj, xs, base);
    hipLaunchKernelGGL(swd_sorty, dim3(n), dim3(THREADS), lds, stream,
                       y, proj, xs, w2, base);
  }
  hipLaunchKernelGGL(swd_final, dim3(1), dim3(64), 0, stream, w2, out);
}

// Round 15
// 1021.447 us; speedup vs baseline: 1.1185x; 1.1185x over previous
//
#include <hip/hip_runtime.h>
#include <math.h>

// Sliced Wasserstein-2: for each (b,c,p): W2^2 = mean_i (sort(X@theta_p) - sort(Y@theta_p))^2
// loss = mean_{b,c} sqrt(mean_p W2^2)
//
// R15 = R13 (best: two-kernel split, merge_high3, sel_ce, VGPR 44, no spill)
// + m=8 cross-lane exchanges via DPP row_ror:8 (on a 16-lane row, ror8 == xor8
// and the m=8 partner never leaves the row). Moves 4 stages x 32 elems = 128
// DS ops/thread/sort from the DS pipe to free DPP operand modifiers, with NO
// new barriers/serialization (the R9/R14 failure mode).
// R14's mid-layout trips REGRESSED (serial legs + barriers beat DS-op savings)
// -> reverted.

namespace {
constexpr int Bb = 8, Cc = 4, Nn = 32768, Pp = 50;
constexpr int THREADS = 1024;
constexpr int VPT = 32;                    // values per thread
constexpr int SLICES = Bb * Cc * Pp;       // 1600
constexpr size_t W2_BYTES = 8192;          // w2[1600] rounded up
constexpr int LDS_FLOATS = Nn + (Nn >> 5); // padded buffer: 33792 floats
}

__device__ __forceinline__ void ce(float& a, float& b, bool up) {
  float lo = fminf(a, b);
  float hi = fmaxf(a, b);
  a = up ? lo : hi;
  b = up ? hi : lo;
}

// 2-VALU compare-select CE: keepMin ? min(v,o) : max(v,o); ties resolve
// consistently on both partners (multiset preserved).
__device__ __forceinline__ float sel_ce(float v, float o, bool keepMin) {
  return ((o < v) != keepMin) ? v : o;
}

// DPP lane move with compile-time control word.
// 0xB1 = quad_perm(1,0,3,2) = xor1; 0x4E = quad_perm(2,3,0,1) = xor2;
// 0x128 = row_ror:8 = xor8 on each 16-lane row.
template<int CTRL>
__device__ __forceinline__ float dpp_move(float x) {
  int i = __builtin_amdgcn_update_dpp(0, __float_as_int(x), CTRL, 0xF, 0xF, true);
  return __int_as_float(i);
}

// cross-lane CE stage with xor-mask M (M=1,2,8 via DPP; M=4,16,32 via bpermute)
template<int M>
__device__ __forceinline__ void stage_xlane(float v[VPT], int tid, bool up) {
  const bool keepMin = (up == ((tid & M) == 0));
  if constexpr (M == 1 || M == 2 || M == 8) {
    constexpr int ctrl = (M == 1) ? 0xB1 : (M == 2) ? 0x4E : 0x128;
#pragma unroll
    for (int r = 0; r < VPT; r++) {
      float o = dpp_move<ctrl>(v[r]);
      v[r] = sel_ce(v[r], o, keepMin);
    }
  } else {
    const int addr = (((tid & 63) ^ M) << 2);
#pragma unroll
    for (int r = 0; r < VPT; r++) {
      float o = __int_as_float(
          __builtin_amdgcn_ds_bpermute(addr, __float_as_int(v[r])));
      v[r] = sel_ce(v[r], o, keepMin);
    }
  }
}

// 5-stage in-register network on the reg-index bits (j=16..1), direction
// uniform per thread via sign-flip trick.
__device__ __forceinline__ void tail_inreg(float v[VPT], bool up) {
  const unsigned flip = up ? 0u : 0x80000000u;
#pragma unroll
  for (int r = 0; r < VPT; r++)
    v[r] = __int_as_float(__float_as_int(v[r]) ^ flip);
#pragma unroll
  for (int j = 16; j > 0; j >>= 1) {
#pragma unroll
    for (int r = 0; r < VPT; r++) {
      if (!(r & j)) {
        float a = v[r], b = v[r | j];
        v[r] = fminf(a, b);
        v[r | j] = fmaxf(a, b);
      }
    }
  }
#pragma unroll
  for (int r = 0; r < VPT; r++)
    v[r] = __int_as_float(__float_as_int(v[r]) ^ flip);
}

// wave-local cross stages (m = MTOP..1) + tail, for merge k = 2^A (A<=12)
template<int A, int MTOP>
__device__ __forceinline__ void wave_stages_and_tail(float v[VPT], int tid) {
  const bool up = ((tid & (1 << (A - 5))) == 0);
  if constexpr (MTOP >= 32) stage_xlane<32>(v, tid, up);
  if constexpr (MTOP >= 16) stage_xlane<16>(v, tid, up);
  if constexpr (MTOP >= 8)  stage_xlane<8>(v, tid, up);
  if constexpr (MTOP >= 4)  stage_xlane<4>(v, tid, up);
  if constexpr (MTOP >= 2)  stage_xlane<2>(v, tid, up);
  if constexpr (MTOP >= 1)  stage_xlane<1>(v, tid, up);
  tail_inreg(v, up);
}

// LDS-exchange stage (wave-crossing xor-mask m on tid), column layout
__device__ __forceinline__ void stage_lds(float v[VPT], float* s, int tid,
                                          int m, bool up) {
  const bool keepMin = (up == ((tid & m) == 0));
  __syncthreads();                        // prior users of s must finish
#pragma unroll
  for (int r = 0; r < VPT; r++) s[r * THREADS + tid] = v[r];
  __syncthreads();
  const int pt = tid ^ m;
#pragma unroll
  for (int r = 0; r < VPT; r++) {
    float o = s[r * THREADS + pt];
    v[r] = sel_ce(v[r], o, keepMin);
  }
}

// Merge k=2^A (A=13..15) entirely in-register via three layouts:
//  L0: i = tid<<5 | r        (reg = i[4:0])
//  L2: i = r2<<10 | tid      (reg = i[14:10]) -> stages b(A-1)..b10
//  L3: i = tid[9:5]<<10 | r3<<5 | tid[4:0] (reg = i[9:5]) -> stages b9..b5
// Caller finishes with tail_inreg in L0 (stages b4..b0).
// Padded addressing Adr(i) = i + (i>>5): every access <=2-way (free).
template<int A>
__device__ __forceinline__ void merge_high3(float v[VPT], float* s, int tid) {
  const int base = tid * VPT;
  // ---- L0 -> L2 ----
  __syncthreads();                      // prior users of s must finish
#pragma unroll
  for (int r = 0; r < VPT; r++) { int i = base + r; s[i + (i >> 5)] = v[r]; }
  __syncthreads();
#pragma unroll
  for (int r2 = 0; r2 < VPT; r2++) { int i = (r2 << 10) | tid; v[r2] = s[i + (i >> 5)]; }
  // ---- stages b(A-1)..b10 on reg bits, compile-time dirs ----
#pragma unroll
  for (int bb = A - 11; bb >= 0; bb--) {
    const int j = 1 << bb;
#pragma unroll
    for (int r2 = 0; r2 < VPT; r2++) {
      if (!(r2 & j)) {
        bool upv = (A == 15) ? true : (((r2 >> (A - 10)) & 1) == 0);
        ce(v[r2], v[r2 | j], upv);
      }
    }
  }
  // ---- L2 -> L3 (rewrite own L2 slots: no barrier before write) ----
#pragma unroll
  for (int r2 = 0; r2 < VPT; r2++) { int i = (r2 << 10) | tid; s[i + (i >> 5)] = v[r2]; }
  __syncthreads();
  const int hi = (tid >> 5) << 10;      // tid[9:5] -> i[14:10]
  const int lo = tid & 31;              // tid[4:0] -> i[4:0]
#pragma unroll
  for (int r3 = 0; r3 < VPT; r3++) { int i = hi | (r3 << 5) | lo; v[r3] = s[i + (i >> 5)]; }
  // ---- stages b9..b5: dir = bit A of i = tid bit (A-5), thread-uniform ----
  const bool up = (A == 15) ? true : ((tid & (1 << (A - 5))) == 0);
  tail_inreg(v, up);
  // ---- L3 -> L0 (rewrite own L3 slots: no barrier before write) ----
#pragma unroll
  for (int r3 = 0; r3 < VPT; r3++) { int i = hi | (r3 << 5) | lo; s[i + (i >> 5)] = v[r3]; }
  __syncthreads();
#pragma unroll
  for (int r = 0; r < VPT; r++) { int i = base + r; v[r] = s[i + (i >> 5)]; }
}

// Full distributed bitonic sort: rank of v[r] on thread tid is tid*32 + r.
__device__ __forceinline__ void sort_dist(float v[VPT], float* s, int tid) {
  // merges a=1..4 (k=2..16): in-register, compile-time directions
#pragma unroll
  for (int k = 2; k <= 16; k <<= 1) {
#pragma unroll
    for (int j = k >> 1; j > 0; j >>= 1) {
#pragma unroll
      for (int r = 0; r < VPT; r++)
        if (!(r & j)) ce(v[r], v[r | j], (r & k) == 0);
    }
  }
  // a=5 (k=32): dir = tid bit0, all stages in-register
  tail_inreg(v, (tid & 1) == 0);
  // a=6..11: wave-local exchanges + tail
  wave_stages_and_tail<6, 1>(v, tid);
  wave_stages_and_tail<7, 2>(v, tid);
  wave_stages_and_tail<8, 4>(v, tid);
  wave_stages_and_tail<9, 8>(v, tid);
  wave_stages_and_tail<10, 16>(v, tid);
  wave_stages_and_tail<11, 32>(v, tid);
  // a=12: one wave-crossing stage (m=64), then wave-local
  stage_lds(v, s, tid, 64, (tid & 128) == 0);
  wave_stages_and_tail<12, 32>(v, tid);
  // a=13..15: three-layout merges (all stages in-register) + L0 tail
  merge_high3<13>(v, s, tid);
  tail_inreg(v, (tid & 256) == 0);
  merge_high3<14>(v, s, tid);
  tail_inreg(v, (tid & 512) == 0);
  merge_high3<15>(v, s, tid);
  tail_inreg(v, true);
}

__device__ __forceinline__ void project_slice(const float4* base, float t0, float t1,
                                              int tid, float v[VPT]) {
#pragma unroll
  for (int q = 0; q < VPT / 2; q++) {
    float4 u = base[tid * (VPT / 2) + q];
    v[2 * q]     = fmaf(u.x, t0, u.y * t1);
    v[2 * q + 1] = fmaf(u.z, t0, u.w * t1);
  }
}

// ---- kernel A: sort X slice, stage sorted run in scratch ----
extern "C" __global__ void __launch_bounds__(THREADS)
swd_sortx(const float* __restrict__ x, const float* __restrict__ proj,
          float* __restrict__ xs, int slice_base) {
  extern __shared__ float s[];
  const int slice = slice_base + blockIdx.x;
  const int p  = slice % Pp;
  const int bc = slice / Pp;
  const int tid = threadIdx.x;
  const float t0 = proj[2 * p];
  const float t1 = proj[2 * p + 1];
  float v[VPT];
  project_slice((const float4*)(x + (size_t)bc * Nn * 2), t0, t1, tid, v);
  sort_dist(v, s, tid);
  float4* o = (float4*)(xs + (size_t)blockIdx.x * Nn + tid * VPT);
#pragma unroll
  for (int q = 0; q < VPT / 4; q++)
    o[q] = make_float4(v[4 * q], v[4 * q + 1], v[4 * q + 2], v[4 * q + 3]);
}

// ---- kernel B: sort Y slice, diff against staged sorted X, reduce ----
extern "C" __global__ void __launch_bounds__(THREADS)
swd_sorty(const float* __restrict__ y, const float* __restrict__ proj,
          const float* __restrict__ xs, float* __restrict__ w2, int slice_base) {
  extern __shared__ float s[];
  __shared__ float wsum[THREADS / 64];
  const int slice = slice_base + blockIdx.x;
  const int p  = slice % Pp;
  const int bc = slice / Pp;
  const int tid = threadIdx.x;
  const float t0 = proj[2 * p];
  const float t1 = proj[2 * p + 1];
  float v[VPT];
  project_slice((const float4*)(y + (size_t)bc * Nn * 2), t0, t1, tid, v);
  sort_dist(v, s, tid);

  const float4* xr = (const float4*)(xs + (size_t)blockIdx.x * Nn + tid * VPT);
  float acc = 0.f;
#pragma unroll
  for (int q = 0; q < VPT / 4; q++) {
    float4 u = xr[q];
    float d0 = u.x - v[4 * q];
    float d1 = u.y - v[4 * q + 1];
    float d2 = u.z - v[4 * q + 2];
    float d3 = u.w - v[4 * q + 3];
    acc = fmaf(d0, d0, acc);
    acc = fmaf(d1, d1, acc);
    acc = fmaf(d2, d2, acc);
    acc = fmaf(d3, d3, acc);
  }
#pragma unroll
  for (int off = 32; off > 0; off >>= 1)
    acc += __shfl_down(acc, off, 64);
  if ((tid & 63) == 0) wsum[tid >> 6] = acc;
  __syncthreads();
  if (tid == 0) {
    float t = 0.f;
#pragma unroll
    for (int w = 0; w < THREADS / 64; w++) t += wsum[w];
    w2[slice] = t * (1.0f / Nn);
  }
}

extern "C" __global__ void swd_final(const float* __restrict__ w2,
                                     float* __restrict__ out) {
  __shared__ float sred[Bb * Cc];
  int t = threadIdx.x;
  if (t < Bb * Cc) {
    float sum = 0.f;
    for (int p = 0; p < Pp; p++) sum += w2[t * Pp + p];
    sred[t] = sqrtf(sum * (1.0f / Pp));
  }
  __syncthreads();
  if (t == 0) {
    float a = 0.f;
    for (int i = 0; i < Bb * Cc; i++) a += sred[i];
    out[0] = a * (1.0f / (Bb * Cc));
  }
}

extern "C" void kernel_launch(void* const* d_in, const int* in_sizes, int n_in,
                              void* d_out, int out_size, void* d_ws, size_t ws_size,
                              hipStream_t stream) {
  const float* x    = (const float*)d_in[0];
  const float* y    = (const float*)d_in[1];
  const float* proj = (const float*)d_in[2];
  float* w2  = (float*)d_ws;                       // first 8KB of scratch
  float* xs  = (float*)((char*)d_ws + W2_BYTES);   // sorted-X staging
  float* out = (float*)d_out;

  const size_t lds = (size_t)LDS_FLOATS * sizeof(float);  // 132 KB
  (void)hipFuncSetAttribute((const void*)swd_sortx,
                            hipFuncAttributeMaxDynamicSharedMemorySize, (int)lds);
  (void)hipFuncSetAttribute((const void*)swd_sorty,
                            hipFuncAttributeMaxDynamicSharedMemorySize, (int)lds);

  const size_t slice_bytes = (size_t)Nn * sizeof(float);
  const size_t avail = ws_size > W2_BYTES ? ws_size - W2_BYTES : 0;
  int chunk = (int)(avail / slice_bytes);
  if (chunk > SLICES) chunk = SLICES;
  if (chunk < 1) chunk = 1;

  for (int base = 0; base < SLICES; base += chunk) {
    int n = SLICES - base < chunk ? SLICES - base : chunk;
    hipLaunchKernelGGL(swd_sortx, dim3(n), dim3(THREADS), lds, stream,
                       x, proj, xs, base);
    hipLaunchKernelGGL(swd_sorty, dim3(n), dim3(THREADS), lds, stream,
                       y, proj, xs, w2, base);
  }
  hipLaunchKernelGGL(swd_final, dim3(1), dim3(64), 0, stream, w2, out);
}

// Round 16
// 1019.714 us; speedup vs baseline: 1.1204x; 1.0017x over previous
//
#include <hip/hip_runtime.h>
#include <math.h>

// Sliced Wasserstein-2: for each (b,c,p): W2^2 = mean_i (sort(X@theta_p) - sort(Y@theta_p))^2
// loss = mean_{b,c} sqrt(mean_p W2^2)
//
// R16 = R15 (two-kernel split, merge_high3, sel_ce, DPP m=1/2/8, VGPR 44,
// no spill) + vectorized L0 transpose legs: pad changed to A4(i)=i+4*(i>>5)
// so each thread's L0 run (32 consecutive floats) starts at 36*tid floats =
// 144B = 16B-aligned -> ds_write_b128/ds_read_b128 (8 ops vs 32). All legs
// stay <=2-way bank aliasing (free). No new barriers (R9/R14 lesson).

namespace {
constexpr int Bb = 8, Cc = 4, Nn = 32768, Pp = 50;
constexpr int THREADS = 1024;
constexpr int VPT = 32;                    // values per thread
constexpr int SLICES = Bb * Cc * Pp;       // 1600
constexpr size_t W2_BYTES = 8192;          // w2[1600] rounded up
constexpr int LDS_FLOATS = Nn + (Nn >> 5) * 4;  // 36864 floats = 144 KB
}

// padded addressing: A4(i) = i + 4*(i>>5); every leg <=2-way (free), and the
// L0 run [tid*32, tid*32+32) maps to 36*tid..36*tid+31 (16B-aligned, dense).
__device__ __forceinline__ int A4(int i) { return i + ((i >> 5) << 2); }

__device__ __forceinline__ void ce(float& a, float& b, bool up) {
  float lo = fminf(a, b);
  float hi = fmaxf(a, b);
  a = up ? lo : hi;
  b = up ? hi : lo;
}

// 2-VALU compare-select CE: keepMin ? min(v,o) : max(v,o); ties resolve
// consistently on both partners (multiset preserved).
__device__ __forceinline__ float sel_ce(float v, float o, bool keepMin) {
  return ((o < v) != keepMin) ? v : o;
}

// DPP lane move with compile-time control word.
// 0xB1 = quad_perm(1,0,3,2) = xor1; 0x4E = quad_perm(2,3,0,1) = xor2;
// 0x128 = row_ror:8 = xor8 on each 16-lane row.
template<int CTRL>
__device__ __forceinline__ float dpp_move(float x) {
  int i = __builtin_amdgcn_update_dpp(0, __float_as_int(x), CTRL, 0xF, 0xF, true);
  return __int_as_float(i);
}

// cross-lane CE stage with xor-mask M (M=1,2,8 via DPP; M=4,16,32 via bpermute)
template<int M>
__device__ __forceinline__ void stage_xlane(float v[VPT], int tid, bool up) {
  const bool keepMin = (up == ((tid & M) == 0));
  if constexpr (M == 1 || M == 2 || M == 8) {
    constexpr int ctrl = (M == 1) ? 0xB1 : (M == 2) ? 0x4E : 0x128;
#pragma unroll
    for (int r = 0; r < VPT; r++) {
      float o = dpp_move<ctrl>(v[r]);
      v[r] = sel_ce(v[r], o, keepMin);
    }
  } else {
    const int addr = (((tid & 63) ^ M) << 2);
#pragma unroll
    for (int r = 0; r < VPT; r++) {
      float o = __int_as_float(
          __builtin_amdgcn_ds_bpermute(addr, __float_as_int(v[r])));
      v[r] = sel_ce(v[r], o, keepMin);
    }
  }
}

// 5-stage in-register network on the reg-index bits (j=16..1), direction
// uniform per thread via sign-flip trick.
__device__ __forceinline__ void tail_inreg(float v[VPT], bool up) {
  const unsigned flip = up ? 0u : 0x80000000u;
#pragma unroll
  for (int r = 0; r < VPT; r++)
    v[r] = __int_as_float(__float_as_int(v[r]) ^ flip);
#pragma unroll
  for (int j = 16; j > 0; j >>= 1) {
#pragma unroll
    for (int r = 0; r < VPT; r++) {
      if (!(r & j)) {
        float a = v[r], b = v[r | j];
        v[r] = fminf(a, b);
        v[r | j] = fmaxf(a, b);
      }
    }
  }
#pragma unroll
  for (int r = 0; r < VPT; r++)
    v[r] = __int_as_float(__float_as_int(v[r]) ^ flip);
}

// wave-local cross stages (m = MTOP..1) + tail, for merge k = 2^A (A<=12)
template<int A, int MTOP>
__device__ __forceinline__ void wave_stages_and_tail(float v[VPT], int tid) {
  const bool up = ((tid & (1 << (A - 5))) == 0);
  if constexpr (MTOP >= 32) stage_xlane<32>(v, tid, up);
  if constexpr (MTOP >= 16) stage_xlane<16>(v, tid, up);
  if constexpr (MTOP >= 8)  stage_xlane<8>(v, tid, up);
  if constexpr (MTOP >= 4)  stage_xlane<4>(v, tid, up);
  if constexpr (MTOP >= 2)  stage_xlane<2>(v, tid, up);
  if constexpr (MTOP >= 1)  stage_xlane<1>(v, tid, up);
  tail_inreg(v, up);
}

// LDS-exchange stage (wave-crossing xor-mask m on tid), column layout
__device__ __forceinline__ void stage_lds(float v[VPT], float* s, int tid,
                                          int m, bool up) {
  const bool keepMin = (up == ((tid & m) == 0));
  __syncthreads();                        // prior users of s must finish
#pragma unroll
  for (int r = 0; r < VPT; r++) s[r * THREADS + tid] = v[r];
  __syncthreads();
  const int pt = tid ^ m;
#pragma unroll
  for (int r = 0; r < VPT; r++) {
    float o = s[r * THREADS + pt];
    v[r] = sel_ce(v[r], o, keepMin);
  }
}

// Merge k=2^A (A=13..15) entirely in-register via three layouts:
//  L0: i = tid<<5 | r        (reg = i[4:0])   <- b128-vectorized legs
//  L2: i = r2<<10 | tid      (reg = i[14:10]) -> stages b(A-1)..b10
//  L3: i = tid[9:5]<<10 | r3<<5 | tid[4:0] (reg = i[9:5]) -> stages b9..b5
// Caller finishes with tail_inreg in L0 (stages b4..b0).
template<int A>
__device__ __forceinline__ void merge_high3(float v[VPT], float* s, int tid) {
  float4* vv = (float4*)v;
  float4* l0 = (float4*)(s + 36 * tid);   // A4(tid*32 + r) = 36*tid + r
  // ---- L0 -> L2 ----
  __syncthreads();                      // prior users of s must finish
#pragma unroll
  for (int q = 0; q < VPT / 4; q++) l0[q] = vv[q];     // 8x ds_write_b128
  __syncthreads();
#pragma unroll
  for (int r2 = 0; r2 < VPT; r2++) { int i = (r2 << 10) | tid; v[r2] = s[A4(i)]; }
  // ---- stages b(A-1)..b10 on reg bits, compile-time dirs ----
#pragma unroll
  for (int bb = A - 11; bb >= 0; bb--) {
    const int j = 1 << bb;
#pragma unroll
    for (int r2 = 0; r2 < VPT; r2++) {
      if (!(r2 & j)) {
        bool upv = (A == 15) ? true : (((r2 >> (A - 10)) & 1) == 0);
        ce(v[r2], v[r2 | j], upv);
      }
    }
  }
  // ---- L2 -> L3 (rewrite own L2 slots: no barrier before write) ----
#pragma unroll
  for (int r2 = 0; r2 < VPT; r2++) { int i = (r2 << 10) | tid; s[A4(i)] = v[r2]; }
  __syncthreads();
  const int hi = (tid >> 5) << 10;      // tid[9:5] -> i[14:10]
  const int lo = tid & 31;              // tid[4:0] -> i[4:0]
#pragma unroll
  for (int r3 = 0; r3 < VPT; r3++) { int i = hi | (r3 << 5) | lo; v[r3] = s[A4(i)]; }
  // ---- stages b9..b5: dir = bit A of i = tid bit (A-5), thread-uniform ----
  const bool up = (A == 15) ? true : ((tid & (1 << (A - 5))) == 0);
  tail_inreg(v, up);
  // ---- L3 -> L0 (rewrite own L3 slots: no barrier before write) ----
#pragma unroll
  for (int r3 = 0; r3 < VPT; r3++) { int i = hi | (r3 << 5) | lo; s[A4(i)] = v[r3]; }
  __syncthreads();
#pragma unroll
  for (int q = 0; q < VPT / 4; q++) vv[q] = l0[q];     // 8x ds_read_b128
}

// Full distributed bitonic sort: rank of v[r] on thread tid is tid*32 + r.
__device__ __forceinline__ void sort_dist(float v[VPT], float* s, int tid) {
  // merges a=1..4 (k=2..16): in-register, compile-time directions
#pragma unroll
  for (int k = 2; k <= 16; k <<= 1) {
#pragma unroll
    for (int j = k >> 1; j > 0; j >>= 1) {
#pragma unroll
      for (int r = 0; r < VPT; r++)
        if (!(r & j)) ce(v[r], v[r | j], (r & k) == 0);
    }
  }
  // a=5 (k=32): dir = tid bit0, all stages in-register
  tail_inreg(v, (tid & 1) == 0);
  // a=6..11: wave-local exchanges + tail
  wave_stages_and_tail<6, 1>(v, tid);
  wave_stages_and_tail<7, 2>(v, tid);
  wave_stages_and_tail<8, 4>(v, tid);
  wave_stages_and_tail<9, 8>(v, tid);
  wave_stages_and_tail<10, 16>(v, tid);
  wave_stages_and_tail<11, 32>(v, tid);
  // a=12: one wave-crossing stage (m=64), then wave-local
  stage_lds(v, s, tid, 64, (tid & 128) == 0);
  wave_stages_and_tail<12, 32>(v, tid);
  // a=13..15: three-layout merges (all stages in-register) + L0 tail
  merge_high3<13>(v, s, tid);
  tail_inreg(v, (tid & 256) == 0);
  merge_high3<14>(v, s, tid);
  tail_inreg(v, (tid & 512) == 0);
  merge_high3<15>(v, s, tid);
  tail_inreg(v, true);
}

__device__ __forceinline__ void project_slice(const float4* base, float t0, float t1,
                                              int tid, float v[VPT]) {
#pragma unroll
  for (int q = 0; q < VPT / 2; q++) {
    float4 u = base[tid * (VPT / 2) + q];
    v[2 * q]     = fmaf(u.x, t0, u.y * t1);
    v[2 * q + 1] = fmaf(u.z, t0, u.w * t1);
  }
}

// ---- kernel A: sort X slice, stage sorted run in scratch ----
extern "C" __global__ void __launch_bounds__(THREADS)
swd_sortx(const float* __restrict__ x, const float* __restrict__ proj,
          float* __restrict__ xs, int slice_base) {
  extern __shared__ float s[];
  const int slice = slice_base + blockIdx.x;
  const int p  = slice % Pp;
  const int bc = slice / Pp;
  const int tid = threadIdx.x;
  const float t0 = proj[2 * p];
  const float t1 = proj[2 * p + 1];
  float v[VPT];
  project_slice((const float4*)(x + (size_t)bc * Nn * 2), t0, t1, tid, v);
  sort_dist(v, s, tid);
  float4* o = (float4*)(xs + (size_t)blockIdx.x * Nn + tid * VPT);
#pragma unroll
  for (int q = 0; q < VPT / 4; q++)
    o[q] = make_float4(v[4 * q], v[4 * q + 1], v[4 * q + 2], v[4 * q + 3]);
}

// ---- kernel B: sort Y slice, diff against staged sorted X, reduce ----
extern "C" __global__ void __launch_bounds__(THREADS)
swd_sorty(const float* __restrict__ y, const float* __restrict__ proj,
          const float* __restrict__ xs, float* __restrict__ w2, int slice_base) {
  extern __shared__ float s[];
  __shared__ float wsum[THREADS / 64];
  const int slice = slice_base + blockIdx.x;
  const int p  = slice % Pp;
  const int bc = slice / Pp;
  const int tid = threadIdx.x;
  const float t0 = proj[2 * p];
  const float t1 = proj[2 * p + 1];
  float v[VPT];
  project_slice((const float4*)(y + (size_t)bc * Nn * 2), t0, t1, tid, v);
  sort_dist(v, s, tid);

  const float4* xr = (const float4*)(xs + (size_t)blockIdx.x * Nn + tid * VPT);
  float acc = 0.f;
#pragma unroll
  for (int q = 0; q < VPT / 4; q++) {
    float4 u = xr[q];
    float d0 = u.x - v[4 * q];
    float d1 = u.y - v[4 * q + 1];
    float d2 = u.z - v[4 * q + 2];
    float d3 = u.w - v[4 * q + 3];
    acc = fmaf(d0, d0, acc);
    acc = fmaf(d1, d1, acc);
    acc = fmaf(d2, d2, acc);
    acc = fmaf(d3, d3, acc);
  }
#pragma unroll
  for (int off = 32; off > 0; off >>= 1)
    acc += __shfl_down(acc, off, 64);
  if ((tid & 63) == 0) wsum[tid >> 6] = acc;
  __syncthreads();
  if (tid == 0) {
    float t = 0.f;
#pragma unroll
    for (int w = 0; w < THREADS / 64; w++) t += wsum[w];
    w2[slice] = t * (1.0f / Nn);
  }
}

extern "C" __global__ void swd_final(const float* __restrict__ w2,
                                     float* __restrict__ out) {
  __shared__ float sred[Bb * Cc];
  int t = threadIdx.x;
  if (t < Bb * Cc) {
    float sum = 0.f;
    for (int p = 0; p < Pp; p++) sum += w2[t * Pp + p];
    sred[t] = sqrtf(sum * (1.0f / Pp));
  }
  __syncthreads();
  if (t == 0) {
    float a = 0.f;
    for (int i = 0; i < Bb * Cc; i++) a += sred[i];
    out[0] = a * (1.0f / (Bb * Cc));
  }
}

extern "C" void kernel_launch(void* const* d_in, const int* in_sizes, int n_in,
                              void* d_out, int out_size, void* d_ws, size_t ws_size,
                              hipStream_t stream) {
  const float* x    = (const float*)d_in[0];
  const float* y    = (const float*)d_in[1];
  const float* proj = (const float*)d_in[2];
  float* w2  = (float*)d_ws;                       // first 8KB of scratch
  float* xs  = (float*)((char*)d_ws + W2_BYTES);   // sorted-X staging
  float* out = (float*)d_out;

  const size_t lds = (size_t)LDS_FLOATS * sizeof(float);  // 144 KB
  (void)hipFuncSetAttribute((const void*)swd_sortx,
                            hipFuncAttributeMaxDynamicSharedMemorySize, (int)lds);
  (void)hipFuncSetAttribute((const void*)swd_sorty,
                            hipFuncAttributeMaxDynamicSharedMemorySize, (int)lds);

  const size_t slice_bytes = (size_t)Nn * sizeof(float);
  const size_t avail = ws_size > W2_BYTES ? ws_size - W2_BYTES : 0;
  int chunk = (int)(avail / slice_bytes);
  if (chunk > SLICES) chunk = SLICES;
  if (chunk < 1) chunk = 1;

  for (int base = 0; base < SLICES; base += chunk) {
    int n = SLICES - base < chunk ? SLICES - base : chunk;
    hipLaunchKernelGGL(swd_sortx, dim3(n), dim3(THREADS), lds, stream,
                       x, proj, xs, base);
    hipLaunchKernelGGL(swd_sorty, dim3(n), dim3(THREADS), lds, stream,
                       y, proj, xs, w2, base);
  }
  hipLaunchKernelGGL(swd_final, dim3(1), dim3(64), 0, stream, w2, out);
}